// Round 8
// baseline (29.448 us; speedup 1.0000x reference)
//
#include <hip/hip_runtime.h>
#include <hip/hip_bf16.h>

// out[b,d] = ortho[d,0]*(var[o,0]^2*ns[b,0]) + ortho[d,1]*(var[o,1]^2*ns[b,1]) + mu[o,d]
//   o = idx[b].  D=128, R=2, NOBJ=9.  img unused.
// HBM-write-bound: ~67 MB NT store + ~9 MB fetch -> ~13 us mixed-stream floor
// (+2-4 us graph/launch overhead).
// R8: R7 exactly, single change — ns loads nontemporal (stream has zero reuse;
// keep it out of L1/L2 so mu/ortho/idx stay hot). idx loads stay regular
// (64B lines reused by 16 consecutive groups).
// Confirmed ledger: 2048 blocks / 32 waves per CU (R5: halving costs +7us),
// NT stores (R6 A/B: -2.5us), pipeline depth & launch_bounds: neutral.

#define VAE_D 128
#define GPB   8    // groups (of 8 rows) per block -> 64 rows/block

typedef float f32x4 __attribute__((ext_vector_type(4)));
typedef float f32x2 __attribute__((ext_vector_type(2)));

__global__ __launch_bounds__(256, 8)   // pins VGPR<=64 -> 8 blocks/CU
void vae_embed_kernel(const int* __restrict__ idx,
                      const float* __restrict__ ns,      // [B, 128]
                      const float* __restrict__ ortho,   // [128, 128] row-major
                      const float* __restrict__ mu,      // [9, 128]
                      const float* __restrict__ var,     // [9, 2]
                      float* __restrict__ out,           // [B, 128]
                      int B)
{
    const int t    = threadIdx.x;
    const int lane = t & 31;            // 32 lanes cover one row (4 floats each)
    const int grp  = t >> 5;            // 8 row-slots per block
    const int d0   = lane << 2;

    // Loop-invariant ortho column pairs (L1-hot after first block per CU).
    const float2 oc0 = *reinterpret_cast<const float2*>(ortho + (size_t)(d0 + 0) * VAE_D);
    const float2 oc1 = *reinterpret_cast<const float2*>(ortho + (size_t)(d0 + 1) * VAE_D);
    const float2 oc2 = *reinterpret_cast<const float2*>(ortho + (size_t)(d0 + 2) * VAE_D);
    const float2 oc3 = *reinterpret_cast<const float2*>(ortho + (size_t)(d0 + 3) * VAE_D);

    const int groups = B >> 3;                 // row-groups of 8
    const int g0 = blockIdx.x * GPB;

    if (g0 + GPB <= groups) {
        // ---- fast path: 8-deep static pipeline ----
        int   o[GPB];
        f32x2 n[GPB];

        #pragma unroll
        for (int u = 0; u < GPB; ++u) {        // phase 1: independent idx loads (regular: line reuse)
            const int b = ((g0 + u) << 3) + grp;
            o[u] = idx[b];
        }
        #pragma unroll
        for (int u = 0; u < GPB; ++u) {        // phase 2: ns loads, nontemporal (zero reuse)
            const int b = ((g0 + u) << 3) + grp;
            n[u] = __builtin_nontemporal_load(
                       reinterpret_cast<const f32x2*>(ns + (size_t)b * VAE_D));
        }
        #pragma unroll
        for (int u = 0; u < GPB; ++u) {        // phase 3: dependent gather+compute+store
            const int b = ((g0 + u) << 3) + grp;
            const float2 v = *reinterpret_cast<const float2*>(var + o[u] * 2);
            const float a0 = v.x * v.x * n[u].x;
            const float a1 = v.y * v.y * n[u].y;
            const float4 m = *reinterpret_cast<const float4*>(mu + (size_t)o[u] * VAE_D + d0);
            f32x4 r;
            r.x = fmaf(oc0.x, a0, fmaf(oc0.y, a1, m.x));
            r.y = fmaf(oc1.x, a0, fmaf(oc1.y, a1, m.y));
            r.z = fmaf(oc2.x, a0, fmaf(oc2.y, a1, m.z));
            r.w = fmaf(oc3.x, a0, fmaf(oc3.y, a1, m.w));
            __builtin_nontemporal_store(r,
                reinterpret_cast<f32x4*>(out + (size_t)b * VAE_D + d0));
        }
    } else {
        // ---- generic tail (unused when B % (8*GPB) == 0) ----
        for (int g = g0; g < groups; ++g) {
            const int b = (g << 3) + grp;
            const int o = idx[b];
            const float2 n01 = *reinterpret_cast<const float2*>(ns + (size_t)b * VAE_D);
            const float2 v   = *reinterpret_cast<const float2*>(var + o * 2);
            const float a0 = v.x * v.x * n01.x;
            const float a1 = v.y * v.y * n01.y;
            const float4 m = *reinterpret_cast<const float4*>(mu + (size_t)o * VAE_D + d0);
            float4 r;
            r.x = fmaf(oc0.x, a0, fmaf(oc0.y, a1, m.x));
            r.y = fmaf(oc1.x, a0, fmaf(oc1.y, a1, m.y));
            r.z = fmaf(oc2.x, a0, fmaf(oc2.y, a1, m.z));
            r.w = fmaf(oc3.x, a0, fmaf(oc3.y, a1, m.w));
            *reinterpret_cast<float4*>(out + (size_t)b * VAE_D + d0) = r;
        }
    }
}

extern "C" void kernel_launch(void* const* d_in, const int* in_sizes, int n_in,
                              void* d_out, int out_size, void* d_ws, size_t ws_size,
                              hipStream_t stream)
{
    // inputs: img[B,4], random_int[B], normal_sample[B,128],
    //         orthogonal_set[128,128], mu_[9,128], var_[9,2]
    const int*   idx   = (const int*)  d_in[1];
    const float* ns    = (const float*)d_in[2];
    const float* ortho = (const float*)d_in[3];
    const float* mu    = (const float*)d_in[4];
    const float* var   = (const float*)d_in[5];
    float* out = (float*)d_out;

    const int B = in_sizes[1];
    const int groups = B >> 3;                         // 16384 for B=131072
    const int grid = (groups + GPB - 1) / GPB;         // 2048 blocks (64 rows each)

    vae_embed_kernel<<<grid, 256, 0, stream>>>(idx, ns, ortho, mu, var, out, B);
}

// Round 9
// 19.900 us; speedup vs baseline: 1.4798x; 1.4798x over previous
//
#include <hip/hip_runtime.h>
#include <hip/hip_bf16.h>

// out[b,d] = ortho[d,0]*(var[o,0]^2*ns[b,0]) + ortho[d,1]*(var[o,1]^2*ns[b,1]) + mu[o,d]
//   o = idx[b].  D=128, R=2, NOBJ=9.  img unused.
// HBM-write-bound. Measured traffic (rocprof, R8 cold dispatch): FETCH 10.6 MB,
// WRITE 68 MB — matches the minimal-traffic model; only rate/overhead remains.
// R9 = exact R4 revert (best measured: 19.97 us).
// Ledger: 2048 blocks/32 waves per CU pinned (R5: halving costs +7 us);
//         NT stores pinned (R6 A/B: -2.5 us);
//         NT input loads REJECTED (R8: +9 us — inputs are L3-resident across
//         replays; nt bypasses Infinity Cache for zero benefit);
//         pipeline depth 8 vs 16, launch_bounds: neutral.

#define VAE_D 128
#define GPB   8    // groups (of 8 rows) per block -> 64 rows/block

typedef float f32x4 __attribute__((ext_vector_type(4)));

__global__ __launch_bounds__(256)
void vae_embed_kernel(const int* __restrict__ idx,
                      const float* __restrict__ ns,      // [B, 128]
                      const float* __restrict__ ortho,   // [128, 128] row-major
                      const float* __restrict__ mu,      // [9, 128]
                      const float* __restrict__ var,     // [9, 2]
                      float* __restrict__ out,           // [B, 128]
                      int B)
{
    const int t    = threadIdx.x;
    const int lane = t & 31;            // 32 lanes cover one row (4 floats each)
    const int grp  = t >> 5;            // 8 row-slots per block
    const int d0   = lane << 2;

    // Loop-invariant ortho column pairs (L1-hot after first block per CU).
    const float2 oc0 = *reinterpret_cast<const float2*>(ortho + (size_t)(d0 + 0) * VAE_D);
    const float2 oc1 = *reinterpret_cast<const float2*>(ortho + (size_t)(d0 + 1) * VAE_D);
    const float2 oc2 = *reinterpret_cast<const float2*>(ortho + (size_t)(d0 + 2) * VAE_D);
    const float2 oc3 = *reinterpret_cast<const float2*>(ortho + (size_t)(d0 + 3) * VAE_D);

    const int groups = B >> 3;                 // row-groups of 8
    const int g0 = blockIdx.x * GPB;

    if (g0 + GPB <= groups) {
        // ---- fast path: 8-deep static pipeline ----
        int    o[GPB];
        float2 n[GPB];

        #pragma unroll
        for (int u = 0; u < GPB; ++u) {        // phase 1: independent idx loads
            const int b = ((g0 + u) << 3) + grp;
            o[u] = idx[b];
        }
        #pragma unroll
        for (int u = 0; u < GPB; ++u) {        // phase 2: independent ns loads
            const int b = ((g0 + u) << 3) + grp;
            n[u] = *reinterpret_cast<const float2*>(ns + (size_t)b * VAE_D);
        }
        #pragma unroll
        for (int u = 0; u < GPB; ++u) {        // phase 3: dependent gather+compute+store
            const int b = ((g0 + u) << 3) + grp;
            const float2 v = *reinterpret_cast<const float2*>(var + o[u] * 2);
            const float a0 = v.x * v.x * n[u].x;
            const float a1 = v.y * v.y * n[u].y;
            const float4 m = *reinterpret_cast<const float4*>(mu + (size_t)o[u] * VAE_D + d0);
            f32x4 r;
            r.x = fmaf(oc0.x, a0, fmaf(oc0.y, a1, m.x));
            r.y = fmaf(oc1.x, a0, fmaf(oc1.y, a1, m.y));
            r.z = fmaf(oc2.x, a0, fmaf(oc2.y, a1, m.z));
            r.w = fmaf(oc3.x, a0, fmaf(oc3.y, a1, m.w));
            __builtin_nontemporal_store(r,
                reinterpret_cast<f32x4*>(out + (size_t)b * VAE_D + d0));
        }
    } else {
        // ---- generic tail (unused when B % (8*GPB) == 0) ----
        for (int g = g0; g < groups; ++g) {
            const int b = (g << 3) + grp;
            const int o = idx[b];
            const float2 n01 = *reinterpret_cast<const float2*>(ns + (size_t)b * VAE_D);
            const float2 v   = *reinterpret_cast<const float2*>(var + o * 2);
            const float a0 = v.x * v.x * n01.x;
            const float a1 = v.y * v.y * n01.y;
            const float4 m = *reinterpret_cast<const float4*>(mu + (size_t)o * VAE_D + d0);
            float4 r;
            r.x = fmaf(oc0.x, a0, fmaf(oc0.y, a1, m.x));
            r.y = fmaf(oc1.x, a0, fmaf(oc1.y, a1, m.y));
            r.z = fmaf(oc2.x, a0, fmaf(oc2.y, a1, m.z));
            r.w = fmaf(oc3.x, a0, fmaf(oc3.y, a1, m.w));
            *reinterpret_cast<float4*>(out + (size_t)b * VAE_D + d0) = r;
        }
    }
}

extern "C" void kernel_launch(void* const* d_in, const int* in_sizes, int n_in,
                              void* d_out, int out_size, void* d_ws, size_t ws_size,
                              hipStream_t stream)
{
    // inputs: img[B,4], random_int[B], normal_sample[B,128],
    //         orthogonal_set[128,128], mu_[9,128], var_[9,2]
    const int*   idx   = (const int*)  d_in[1];
    const float* ns    = (const float*)d_in[2];
    const float* ortho = (const float*)d_in[3];
    const float* mu    = (const float*)d_in[4];
    const float* var   = (const float*)d_in[5];
    float* out = (float*)d_out;

    const int B = in_sizes[1];
    const int groups = B >> 3;                         // 16384 for B=131072
    const int grid = (groups + GPB - 1) / GPB;         // 2048 blocks (64 rows each)

    vae_embed_kernel<<<grid, 256, 0, stream>>>(idx, ns, ortho, mu, var, out, B);
}

// Round 10
// 18.791 us; speedup vs baseline: 1.5672x; 1.0591x over previous
//
#include <hip/hip_runtime.h>
#include <hip/hip_bf16.h>

// out[b,d] = ortho[d,0]*(var[o,0]^2*ns[b,0]) + ortho[d,1]*(var[o,1]^2*ns[b,1]) + mu[o,d]
//   o = idx[b].  D=128, R=2, NOBJ=9.  img unused.
// R10: clean grid test — GPB=16 / 1024 blocks, REGULAR loads, NT stores.
// (R5 confounded grid-halving with NT loads; R8 showed NT ns-loads alone
// cost +9.4 us, so grid size is actually untested. This disconfounds.)
// Ledger: NT stores -2.5 us (R6 A/B); NT input loads +9.4 us REJECTED (R8);
//         VGPR=32 -> occupancy never register-limited (R8 profile).

#define VAE_D 128
#define GPB   16   // groups (of 8 rows) per block -> 128 rows/block

typedef float f32x4 __attribute__((ext_vector_type(4)));

__global__ __launch_bounds__(256)
void vae_embed_kernel(const int* __restrict__ idx,
                      const float* __restrict__ ns,      // [B, 128]
                      const float* __restrict__ ortho,   // [128, 128] row-major
                      const float* __restrict__ mu,      // [9, 128]
                      const float* __restrict__ var,     // [9, 2]
                      float* __restrict__ out,           // [B, 128]
                      int B)
{
    const int t    = threadIdx.x;
    const int lane = t & 31;            // 32 lanes cover one row (4 floats each)
    const int grp  = t >> 5;            // 8 row-slots per block
    const int d0   = lane << 2;

    // Loop-invariant ortho column pairs (L1-hot after first block per CU).
    const float2 oc0 = *reinterpret_cast<const float2*>(ortho + (size_t)(d0 + 0) * VAE_D);
    const float2 oc1 = *reinterpret_cast<const float2*>(ortho + (size_t)(d0 + 1) * VAE_D);
    const float2 oc2 = *reinterpret_cast<const float2*>(ortho + (size_t)(d0 + 2) * VAE_D);
    const float2 oc3 = *reinterpret_cast<const float2*>(ortho + (size_t)(d0 + 3) * VAE_D);

    const int groups = B >> 3;                 // row-groups of 8
    const int g0 = blockIdx.x * GPB;

    if (g0 + GPB <= groups) {
        // ---- fast path: 16-deep static pipeline ----
        int    o[GPB];
        float2 n[GPB];

        #pragma unroll
        for (int u = 0; u < GPB; ++u) {        // phase 1: independent idx loads
            const int b = ((g0 + u) << 3) + grp;
            o[u] = idx[b];
        }
        #pragma unroll
        for (int u = 0; u < GPB; ++u) {        // phase 2: independent ns loads
            const int b = ((g0 + u) << 3) + grp;
            n[u] = *reinterpret_cast<const float2*>(ns + (size_t)b * VAE_D);
        }
        #pragma unroll
        for (int u = 0; u < GPB; ++u) {        // phase 3: dependent gather+compute+store
            const int b = ((g0 + u) << 3) + grp;
            const float2 v = *reinterpret_cast<const float2*>(var + o[u] * 2);
            const float a0 = v.x * v.x * n[u].x;
            const float a1 = v.y * v.y * n[u].y;
            const float4 m = *reinterpret_cast<const float4*>(mu + (size_t)o[u] * VAE_D + d0);
            f32x4 r;
            r.x = fmaf(oc0.x, a0, fmaf(oc0.y, a1, m.x));
            r.y = fmaf(oc1.x, a0, fmaf(oc1.y, a1, m.y));
            r.z = fmaf(oc2.x, a0, fmaf(oc2.y, a1, m.z));
            r.w = fmaf(oc3.x, a0, fmaf(oc3.y, a1, m.w));
            __builtin_nontemporal_store(r,
                reinterpret_cast<f32x4*>(out + (size_t)b * VAE_D + d0));
        }
    } else {
        // ---- generic tail (unused when B % (8*GPB) == 0) ----
        for (int g = g0; g < groups; ++g) {
            const int b = (g << 3) + grp;
            const int o = idx[b];
            const float2 n01 = *reinterpret_cast<const float2*>(ns + (size_t)b * VAE_D);
            const float2 v   = *reinterpret_cast<const float2*>(var + o * 2);
            const float a0 = v.x * v.x * n01.x;
            const float a1 = v.y * v.y * n01.y;
            const float4 m = *reinterpret_cast<const float4*>(mu + (size_t)o * VAE_D + d0);
            float4 r;
            r.x = fmaf(oc0.x, a0, fmaf(oc0.y, a1, m.x));
            r.y = fmaf(oc1.x, a0, fmaf(oc1.y, a1, m.y));
            r.z = fmaf(oc2.x, a0, fmaf(oc2.y, a1, m.z));
            r.w = fmaf(oc3.x, a0, fmaf(oc3.y, a1, m.w));
            *reinterpret_cast<float4*>(out + (size_t)b * VAE_D + d0) = r;
        }
    }
}

extern "C" void kernel_launch(void* const* d_in, const int* in_sizes, int n_in,
                              void* d_out, int out_size, void* d_ws, size_t ws_size,
                              hipStream_t stream)
{
    // inputs: img[B,4], random_int[B], normal_sample[B,128],
    //         orthogonal_set[128,128], mu_[9,128], var_[9,2]
    const int*   idx   = (const int*)  d_in[1];
    const float* ns    = (const float*)d_in[2];
    const float* ortho = (const float*)d_in[3];
    const float* mu    = (const float*)d_in[4];
    const float* var   = (const float*)d_in[5];
    float* out = (float*)d_out;

    const int B = in_sizes[1];
    const int groups = B >> 3;                         // 16384 for B=131072
    const int grid = (groups + GPB - 1) / GPB;         // 1024 blocks (128 rows each)

    vae_embed_kernel<<<grid, 256, 0, stream>>>(idx, ns, ortho, mu, var, out, B);
}

// Round 11
// 18.752 us; speedup vs baseline: 1.5704x; 1.0021x over previous
//
#include <hip/hip_runtime.h>
#include <hip/hip_bf16.h>

// out[b,d] = ortho[d,0]*(var[o,0]^2*ns[b,0]) + ortho[d,1]*(var[o,1]^2*ns[b,1]) + mu[o,d]
//   o = idx[b].  D=128, R=2, NOBJ=9.  img unused.
// R11: GPB 16->32 (512 blocks, 256 rows/block) — continuing the R10 trend
// (1024/GPB16 = 18.79 < 2048/GPB8 = 19.90): deeper per-thread static pipeline
// + fewer block ramps beats raw TLP. Single variable vs R10.
// Ledger: NT stores -2.5us (R6); NT input loads REJECTED +9.4us (R8);
//         grid 2048->1024 with deeper pipe: -1.1us (R10); VGPR never limiting.

#define VAE_D 128
#define GPB   32   // groups (of 8 rows) per block -> 256 rows/block

typedef float f32x4 __attribute__((ext_vector_type(4)));

__global__ __launch_bounds__(256)
void vae_embed_kernel(const int* __restrict__ idx,
                      const float* __restrict__ ns,      // [B, 128]
                      const float* __restrict__ ortho,   // [128, 128] row-major
                      const float* __restrict__ mu,      // [9, 128]
                      const float* __restrict__ var,     // [9, 2]
                      float* __restrict__ out,           // [B, 128]
                      int B)
{
    const int t    = threadIdx.x;
    const int lane = t & 31;            // 32 lanes cover one row (4 floats each)
    const int grp  = t >> 5;            // 8 row-slots per block
    const int d0   = lane << 2;

    // Loop-invariant ortho column pairs (L1-hot after first block per CU).
    const float2 oc0 = *reinterpret_cast<const float2*>(ortho + (size_t)(d0 + 0) * VAE_D);
    const float2 oc1 = *reinterpret_cast<const float2*>(ortho + (size_t)(d0 + 1) * VAE_D);
    const float2 oc2 = *reinterpret_cast<const float2*>(ortho + (size_t)(d0 + 2) * VAE_D);
    const float2 oc3 = *reinterpret_cast<const float2*>(ortho + (size_t)(d0 + 3) * VAE_D);

    const int groups = B >> 3;                 // row-groups of 8
    const int g0 = blockIdx.x * GPB;

    if (g0 + GPB <= groups) {
        // ---- fast path: 32-deep static pipeline ----
        int    o[GPB];
        float2 n[GPB];

        #pragma unroll
        for (int u = 0; u < GPB; ++u) {        // phase 1: independent idx loads
            const int b = ((g0 + u) << 3) + grp;
            o[u] = idx[b];
        }
        #pragma unroll
        for (int u = 0; u < GPB; ++u) {        // phase 2: independent ns loads
            const int b = ((g0 + u) << 3) + grp;
            n[u] = *reinterpret_cast<const float2*>(ns + (size_t)b * VAE_D);
        }
        #pragma unroll
        for (int u = 0; u < GPB; ++u) {        // phase 3: dependent gather+compute+store
            const int b = ((g0 + u) << 3) + grp;
            const float2 v = *reinterpret_cast<const float2*>(var + o[u] * 2);
            const float a0 = v.x * v.x * n[u].x;
            const float a1 = v.y * v.y * n[u].y;
            const float4 m = *reinterpret_cast<const float4*>(mu + (size_t)o[u] * VAE_D + d0);
            f32x4 r;
            r.x = fmaf(oc0.x, a0, fmaf(oc0.y, a1, m.x));
            r.y = fmaf(oc1.x, a0, fmaf(oc1.y, a1, m.y));
            r.z = fmaf(oc2.x, a0, fmaf(oc2.y, a1, m.z));
            r.w = fmaf(oc3.x, a0, fmaf(oc3.y, a1, m.w));
            __builtin_nontemporal_store(r,
                reinterpret_cast<f32x4*>(out + (size_t)b * VAE_D + d0));
        }
    } else {
        // ---- generic tail (unused when B % (8*GPB) == 0) ----
        for (int g = g0; g < groups; ++g) {
            const int b = (g << 3) + grp;
            const int o = idx[b];
            const float2 n01 = *reinterpret_cast<const float2*>(ns + (size_t)b * VAE_D);
            const float2 v   = *reinterpret_cast<const float2*>(var + o * 2);
            const float a0 = v.x * v.x * n01.x;
            const float a1 = v.y * v.y * n01.y;
            const float4 m = *reinterpret_cast<const float4*>(mu + (size_t)o * VAE_D + d0);
            float4 r;
            r.x = fmaf(oc0.x, a0, fmaf(oc0.y, a1, m.x));
            r.y = fmaf(oc1.x, a0, fmaf(oc1.y, a1, m.y));
            r.z = fmaf(oc2.x, a0, fmaf(oc2.y, a1, m.z));
            r.w = fmaf(oc3.x, a0, fmaf(oc3.y, a1, m.w));
            *reinterpret_cast<float4*>(out + (size_t)b * VAE_D + d0) = r;
        }
    }
}

extern "C" void kernel_launch(void* const* d_in, const int* in_sizes, int n_in,
                              void* d_out, int out_size, void* d_ws, size_t ws_size,
                              hipStream_t stream)
{
    // inputs: img[B,4], random_int[B], normal_sample[B,128],
    //         orthogonal_set[128,128], mu_[9,128], var_[9,2]
    const int*   idx   = (const int*)  d_in[1];
    const float* ns    = (const float*)d_in[2];
    const float* ortho = (const float*)d_in[3];
    const float* mu    = (const float*)d_in[4];
    const float* var   = (const float*)d_in[5];
    float* out = (float*)d_out;

    const int B = in_sizes[1];
    const int groups = B >> 3;                         // 16384 for B=131072
    const int grid = (groups + GPB - 1) / GPB;         // 512 blocks (256 rows each)

    vae_embed_kernel<<<grid, 256, 0, stream>>>(idx, ns, ortho, mu, var, out, B);
}